// Round 4
// baseline (159.412 us; speedup 1.0000x reference)
//
#include <hip/hip_runtime.h>

#define DIN 96
#define DP 48
#define NPOS (48*48*48)   // 110592
#define NG 1728           // 12^3
#define WIN3 343
#define NCH 64
#define NC2 32

// ---------------------------------------------------------------------------
// Kernel A: depthwise 3x3x3 stride-2 pad-1 conv + bias -> dwout[c][pos]
// Each thread computes a 2(d) x 1(h) x 4(w) output micro-tile.
// Per input row: two aligned float4 + 1 scalar (9 floats -> 4 w-outputs),
// 15 rows (5 planes x 3 rows) -> 45 loads, 8 independent accumulators.
// ---------------------------------------------------------------------------
__global__ __launch_bounds__(256) void dwconv8(
    const float* __restrict__ feat,   // [64][96][96][96]
    const float* __restrict__ dw_w,   // [64][27]
    const float* __restrict__ dw_b,   // [64]
    float* __restrict__ dwout)        // [64][NPOS]
{
    const int c   = blockIdx.y;
    const int idx = blockIdx.x * 256 + threadIdx.x;   // 0..13823
    const int t   = idx % 12;                         // w-quad (out w = 4t..4t+3)
    const int oh  = (idx / 12) % 48;
    const int odp = idx / (12 * 48);                  // d-pair (out d = 2odp,2odp+1)

    const float* fc = feat + (size_t)c * (DIN * DIN * DIN);
    const float* wc = dw_w + c * 27;
    float w[27];
    #pragma unroll
    for (int i = 0; i < 27; ++i) w[i] = wc[i];        // wave-uniform

    float acc[2][4];
    #pragma unroll
    for (int i = 0; i < 2; ++i)
        #pragma unroll
        for (int j = 0; j < 4; ++j) acc[i][j] = 0.0f;

    #pragma unroll
    for (int dd = 0; dd < 5; ++dd) {
        const int id = 4 * odp - 1 + dd;              // input plane
        if (id >= 0) {
            #pragma unroll
            for (int kh = 0; kh < 3; ++kh) {
                const int ih = 2 * oh - 1 + kh;       // input row
                if (ih >= 0) {
                    const float* row = fc + ((size_t)id * DIN + ih) * DIN + 8 * t;
                    const float4 a4 = *(const float4*)(row);
                    const float4 b4 = *(const float4*)(row + 4);
                    const float  s  = (t > 0) ? row[-1] : 0.0f;   // w = 8t-1 (pad 0)
                    #pragma unroll
                    for (int half = 0; half < 2; ++half) {
                        if ((half == 0 && dd <= 2) || (half == 1 && dd >= 2)) {
                            const int kd = (half == 0) ? dd : dd - 2;
                            const float w0 = w[(kd * 3 + kh) * 3 + 0];
                            const float w1 = w[(kd * 3 + kh) * 3 + 1];
                            const float w2 = w[(kd * 3 + kh) * 3 + 2];
                            acc[half][0] = fmaf(s,    w0, fmaf(a4.x, w1, fmaf(a4.y, w2, acc[half][0])));
                            acc[half][1] = fmaf(a4.y, w0, fmaf(a4.z, w1, fmaf(a4.w, w2, acc[half][1])));
                            acc[half][2] = fmaf(a4.w, w0, fmaf(b4.x, w1, fmaf(b4.y, w2, acc[half][2])));
                            acc[half][3] = fmaf(b4.y, w0, fmaf(b4.z, w1, fmaf(b4.w, w2, acc[half][3])));
                        }
                    }
                }
            }
        }
    }

    const float b = dw_b[c];
    const size_t base = (size_t)c * NPOS + (((size_t)(2 * odp) * DP + oh) * DP) + 4 * t;
    *(float4*)(dwout + base)           = make_float4(acc[0][0] + b, acc[0][1] + b, acc[0][2] + b, acc[0][3] + b);
    *(float4*)(dwout + base + DP * DP) = make_float4(acc[1][0] + b, acc[1][1] + b, acc[1][2] + b, acc[1][3] + b);
}

// ---------------------------------------------------------------------------
// Kernel B: pointwise (64->32)+bias+ReLU, V projection (32->64) -> V[pos][64],
//           K score rows {0,32} * 1/sqrt(32) -> Ksc[2][NPOS]
// ---------------------------------------------------------------------------
__global__ __launch_bounds__(256) void pwproj(
    const float* __restrict__ dwout,  // [64][NPOS]
    const float* __restrict__ pw_w,   // [32][64]
    const float* __restrict__ pw_b,   // [32]
    const float* __restrict__ k_w,    // [64][32]
    const float* __restrict__ v_w,    // [64][32]
    float* __restrict__ V,            // [NPOS][64]
    float* __restrict__ Ksc)          // [2][NPOS]
{
    const int pos = blockIdx.x * 256 + threadIdx.x;

    float f2[NC2];
    #pragma unroll
    for (int o = 0; o < NC2; ++o) f2[o] = pw_b[o];

    #pragma unroll 16
    for (int c = 0; c < NCH; ++c) {
        float x = dwout[(size_t)c * NPOS + pos];
        #pragma unroll
        for (int o = 0; o < NC2; ++o)
            f2[o] = fmaf(pw_w[o * NCH + c], x, f2[o]);
    }

    #pragma unroll
    for (int o = 0; o < NC2; ++o) f2[o] = fmaxf(f2[o], 0.0f);

    float4* vout = (float4*)(V + (size_t)pos * NCH);
    #pragma unroll
    for (int j4 = 0; j4 < NCH / 4; ++j4) {
        float4 r;
        float* rp = (float*)&r;
        #pragma unroll
        for (int q = 0; q < 4; ++q) {
            int j = j4 * 4 + q;
            float a = 0.0f;
            #pragma unroll
            for (int o = 0; o < NC2; ++o) a = fmaf(v_w[j * NC2 + o], f2[o], a);
            rp[q] = a;
        }
        vout[j4] = r;
    }

    const float scale = 0.17677669529663687f;
    #pragma unroll
    for (int h = 0; h < 2; ++h) {
        float a = 0.0f;
        #pragma unroll
        for (int o = 0; o < NC2; ++o) a = fmaf(k_w[(h * 32) * NC2 + o], f2[o], a);
        Ksc[h * NPOS + pos] = a * scale;
    }
}

// ---------------------------------------------------------------------------
// Kernel 2: per-center windowed attention + output head.
// Heads processed in PARALLEL: waves 0-1 -> head 0, waves 2-3 -> head 1.
// ---------------------------------------------------------------------------
__global__ __launch_bounds__(256) void attn_out(
    const float* __restrict__ V,      // [NPOS][64]
    const float* __restrict__ Ksc,    // [2][NPOS]
    const float* __restrict__ out_w,  // [3][64]
    const float* __restrict__ out_b,  // [3]
    float* __restrict__ out)          // [3][NG]
{
    const int lo_t[12] = {0,1,5,9,14,18,22,26,31,35,39,44};
    const int hi_t[12] = {4,8,12,16,21,25,29,33,38,42,46,48};

    const int g    = blockIdx.x;
    const int tid  = threadIdx.x;
    const int lane = tid & 63;
    const int wv   = tid >> 6;
    const int h    = wv >> 1;         // score-phase head
    const int p    = tid & 127;       // index within head pair, 0..127

    const int gz = g % 12, gy = (g / 12) % 12, gx = g / 144;
    const int lox = lo_t[gx], hix = hi_t[gx];
    const int loy = lo_t[gy], hiy = hi_t[gy];
    const int loz = lo_t[gz], hiz = hi_t[gz];

    __shared__ int   s_flat[WIN3];        // bit31 set => masked out
    __shared__ float s_attn[2][WIN3];
    __shared__ float s_red[4];
    __shared__ float s_red2[4];
    __shared__ float s_gsum[2];
    __shared__ float s_pctx[4][NCH];
    __shared__ float s_ctx[NCH];

    for (int w = tid; w < WIN3; w += 256) {
        int kd = w / 49, kh = (w / 7) % 7, kw = w % 7;
        int ix = lox + kd, iy = loy + kh, iz = loz + kw;
        bool m = (ix < hix) && (iy < hiy) && (iz < hiz);
        if (ix >= hix) ix = lox;
        if (iy >= hiy) iy = loy;
        if (iz >= hiz) iz = loz;
        int flat = (ix * DP + iy) * DP + iz;
        s_flat[w] = m ? flat : (flat | (int)0x80000000);
    }
    __syncthreads();

    const float NEG_INF = -__builtin_inff();

    // gather scores for my head: slots p, p+128, p+256
    float sc0 = NEG_INF, sc1 = NEG_INF, sc2 = NEG_INF;
    {
        int fv = s_flat[p];
        if (fv >= 0) sc0 = Ksc[h * NPOS + fv];
        fv = s_flat[p + 128];
        if (fv >= 0) sc1 = Ksc[h * NPOS + fv];
        if (p + 256 < WIN3) {
            fv = s_flat[p + 256];
            if (fv >= 0) sc2 = Ksc[h * NPOS + fv];
        }
    }

    float lmax = fmaxf(fmaxf(sc0, sc1), sc2);
    #pragma unroll
    for (int off = 32; off; off >>= 1) lmax = fmaxf(lmax, __shfl_xor(lmax, off));
    if (lane == 0) s_red[wv] = lmax;
    __syncthreads();
    const float gmax = fmaxf(s_red[2 * h], s_red[2 * h + 1]);

    float e0 = (sc0 == NEG_INF) ? 0.0f : expf(sc0 - gmax);
    float e1 = (sc1 == NEG_INF) ? 0.0f : expf(sc1 - gmax);
    float e2 = 0.0f;
    s_attn[h][p]       = e0;
    s_attn[h][p + 128] = e1;
    if (p + 256 < WIN3) {
        e2 = (sc2 == NEG_INF) ? 0.0f : expf(sc2 - gmax);
        s_attn[h][p + 256] = e2;
    }
    float lsum = e0 + e1 + e2;
    #pragma unroll
    for (int off = 32; off; off >>= 1) lsum += __shfl_xor(lsum, off);
    if (lane == 0) s_red2[wv] = lsum;
    __syncthreads();
    if (tid < 2) s_gsum[tid] = s_red2[2 * tid] + s_red2[2 * tid + 1];
    __syncthreads();

    // PV: lane j = hh*32+c ; waves stride the window
    const int hh = lane >> 5;
    float acc = 0.0f;
    for (int w = wv; w < WIN3; w += 4) {
        int fv = s_flat[w] & 0x7fffffff;
        acc = fmaf(s_attn[hh][w], V[(size_t)fv * NCH + lane], acc);
    }

    s_pctx[wv][lane] = acc;
    __syncthreads();
    if (wv == 0) {
        float ctx = s_pctx[0][lane] + s_pctx[1][lane] + s_pctx[2][lane] + s_pctx[3][lane];
        s_ctx[lane] = ctx / s_gsum[hh];
    }
    __syncthreads();

    if (tid < 3) {
        float a = out_b[tid];
        #pragma unroll
        for (int j = 0; j < NCH; ++j) a = fmaf(out_w[tid * NCH + j], s_ctx[j], a);
        out[tid * NG + g] = a;
    }
}

// ---------------------------------------------------------------------------
extern "C" void kernel_launch(void* const* d_in, const int* in_sizes, int n_in,
                              void* d_out, int out_size, void* d_ws, size_t ws_size,
                              hipStream_t stream) {
    const float* feat  = (const float*)d_in[0];
    const float* dw_w  = (const float*)d_in[1];
    const float* dw_b  = (const float*)d_in[2];
    const float* pw_w  = (const float*)d_in[3];
    const float* pw_b  = (const float*)d_in[4];
    const float* k_w   = (const float*)d_in[5];
    const float* v_w   = (const float*)d_in[6];
    const float* out_w = (const float*)d_in[7];
    const float* out_b = (const float*)d_in[8];
    float* out = (float*)d_out;

    float* dwout = (float*)d_ws;                        // [64][NPOS]
    float* V     = dwout + (size_t)NCH * NPOS;          // [NPOS][64]
    float* Ksc   = V + (size_t)NPOS * NCH;              // [2][NPOS]

    // dwconv8: 13824 threads/channel = 54 blocks of 256; grid (54, 64)
    hipLaunchKernelGGL(dwconv8, dim3(54, NCH), dim3(256), 0, stream,
                       feat, dw_w, dw_b, dwout);
    hipLaunchKernelGGL(pwproj, dim3(NPOS / 256), dim3(256), 0, stream,
                       dwout, pw_w, pw_b, k_w, v_w, V, Ksc);
    hipLaunchKernelGGL(attn_out, dim3(NG), dim3(256), 0, stream,
                       V, Ksc, out_w, out_b, out);
}